// Round 1
// 2132.630 us; speedup vs baseline: 1.2504x; 1.2504x over previous
//
#include <hip/hip_runtime.h>
#include <math.h>

typedef unsigned short u16;
typedef unsigned long long u64;
typedef __attribute__((ext_vector_type(8))) short bf16x8;   // MFMA A/B frag
typedef __attribute__((ext_vector_type(4))) float f32x4;    // MFMA C/D frag

#define T_STEPS 32
#define BSZ     32
#define N_IN    64
#define H       256
#define N_OUT   64
#define ESTRIDE 9984              // rows = 320*31 + 64 (final fresh block)
#define CLAMP_MIN (-2.0f)
#define CLAMP_MAX ( 2.0f)
#define GNB 16                    // gemm blocks per sample

// ---------------------------------------------------------------------------
// Fragment-packed layout "B" (8B-quad granular):
//   element (row R, k):  RT=R>>4, m=R&15, KC=k>>5, qq=(k&31)>>3, h=(k&7)>>2, v=k&3
//   u16 offset = ((RT*8+KC)*4+qq)*128 + m*8 + h*4 + v
// Properties:
//   * A/B-frag load (lane l: m=l&15,q=l>>4) for (RT,KC) = ONE contiguous 16B at
//     ((RT*8+KC)*4+q)*256 + m*16  (ds_read_b128 / global dwordx4, conflict-free)
//   * C^T store (operand-swapped mfma): lane's 4 acc values = 8B contiguous;
//     a wave's 64x8B covers 512B contiguous -> fully coalesced dwordx2 stores.
// ---------------------------------------------------------------------------

__device__ inline u16 f2bf(float x) {                       // RTNE fp32->bf16
    unsigned u = __builtin_bit_cast(unsigned, x);
    unsigned r = u + 0x7FFFu + ((u >> 16) & 1u);
    return (u16)(r >> 16);
}

__device__ __forceinline__ void gl_lds16(const u16* g, u16* l) {
    __builtin_amdgcn_global_load_lds(
        (const __attribute__((address_space(1))) unsigned int*)g,
        (__attribute__((address_space(3))) unsigned int*)l,
        16, 0, 0);
}

// ---------------------------------------------------------------------------
__global__ void init_k(float* __restrict__ radT) {          // zero [T][B][H]
    int i = blockIdx.x * 256 + threadIdx.x;
    radT[i] = 0.0f;
}

// ---------------------------------------------------------------------------
__global__ void transpose_k(const float* __restrict__ src, float* __restrict__ dst,
                            int R, int C)
{
    __shared__ float tile[32][33];
    int bi = blockIdx.y, bj = blockIdx.x;
    int r0 = threadIdx.x >> 5, c = threadIdx.x & 31;
    #pragma unroll
    for (int rr = 0; rr < 4; ++rr) {
        int r = r0 * 4 + rr;
        tile[r][c] = src[(bi * 32 + r) * C + bj * 32 + c];
    }
    __syncthreads();
    #pragma unroll
    for (int rr = 0; rr < 4; ++rr) {
        int r = r0 * 4 + rr;
        dst[(bj * 32 + r) * R + bi * 32 + c] = tile[c][r];
    }
}

// ---------------------------------------------------------------------------
// prefresh: fresh rows (rho_t * Wih) for ALL t, plus their rad contribution.
// Depends only on X/eps -> hoisted out of the t-loop. grid (T_STEPS, Bc).
// ---------------------------------------------------------------------------
__global__ __launch_bounds__(256) void prefresh_k(
    const float* __restrict__ X, const float* __restrict__ eps,
    const float* __restrict__ Wih, u16* __restrict__ err,
    float* __restrict__ radT)
{
    __shared__ float rho_s[N_IN], rad_s[H];
    const int t = blockIdx.x, bi = blockIdx.y, tid = threadIdx.x;
    if (tid < N_IN) {
        float x = X[((size_t)t * BSZ + bi) * N_IN + tid], e = eps[bi];
        float lo = fmaxf(x - e, CLAMP_MIN), up = fminf(x + e, CLAMP_MAX);
        rho_s[tid] = 0.5f * (up - lo);
    }
    rad_s[tid] = 0.f;
    __syncthreads();

    u16* dst = err + (size_t)bi * ESTRIDE * H + (size_t)(20 * t) * 4096; // row 320t
    #pragma unroll 4
    for (int iter = 0; iter < 32; ++iter) {
        int p = iter * 256 + tid;                 // 4B-pair index in 64x256 block
        int vb = (p & 1) * 2, h = (p >> 1) & 1, m = (p >> 2) & 15, qq = (p >> 6) & 3;
        int KC = (p >> 8) & 7, RT = p >> 11;
        int i = RT * 16 + m, k = KC * 32 + qq * 8 + h * 4 + vb;
        float rho = rho_s[i];
        float v0 = rho * Wih[(size_t)i * H + k];
        float v1 = rho * Wih[(size_t)i * H + k + 1];
        *(unsigned*)&dst[2 * p] = (unsigned)f2bf(v0) | ((unsigned)f2bf(v1) << 16);
        atomicAdd(&rad_s[k],     fabsf(v0));
        atomicAdd(&rad_s[k + 1], fabsf(v1));
    }
    __syncthreads();
    atomicAdd(&radT[(size_t)t * BSZ * H + (size_t)bi * H + tid], rad_s[tid]);
}

// ---------------------------------------------------------------------------
// prep0: head preactivation at t=0 only (fresh rows handled by prefresh).
// ---------------------------------------------------------------------------
__global__ __launch_bounds__(256) void prep0_k(
    const float* __restrict__ X0, const float* __restrict__ eps,
    const float* __restrict__ Wih, const float* __restrict__ bih,
    const float* __restrict__ bhh, float* __restrict__ hp0)
{
    __shared__ float hx[N_IN];
    const int b = blockIdx.x, tid = threadIdx.x;
    if (tid < N_IN) {
        float x = X0[b * N_IN + tid], e = eps[b];
        float l = fmaxf(x - e, CLAMP_MIN), u = fminf(x + e, CLAMP_MAX);
        hx[tid] = 0.5f * (l + u);
    }
    __syncthreads();
    float acc = bih[tid] + bhh[tid];
    #pragma unroll 8
    for (int i = 0; i < N_IN; ++i) acc += hx[i] * Wih[i * H + tid];
    hp0[b * H + tid] = acc;
}

// ---------------------------------------------------------------------------
// mid_k (t>=1): tanh(prev) + WT pack (lam folded) + diag rows + head GEMV.
// grid (9, Bc): roles 0..7 = WT/diag slice (linear-decode writers), 8 = head.
// ---------------------------------------------------------------------------
__global__ __launch_bounds__(256) void mid_k(
    const float* __restrict__ Xt, const float* __restrict__ eps,
    const float* __restrict__ Wih, const float* __restrict__ Whh,
    const float* __restrict__ WhhT32,
    const float* __restrict__ bih, const float* __restrict__ bhh,
    const float* __restrict__ hp_prev, const float* __restrict__ rad_prev,
    float* __restrict__ hp_new, float* __restrict__ rad_new,
    u16* __restrict__ err, u16* __restrict__ WTp, int E_old)
{
    __shared__ float lam_s[H], de_s[H], aux_s[H], hxr[N_IN];
    const int role = blockIdx.x, b = blockIdx.y, tid = threadIdx.x;

    float hd = hp_prev[b * H + tid], r = rad_prev[b * H + tid];
    float l = hd - r, u = hd + r;
    float tl = tanhf(l), tu = tanhf(u);
    float la = fminf(1.f - tl * tl, 1.f - tu * tu);
    float mu = 0.5f * (tu + tl - la * (u + l));
    float dd = 0.5f * (tu - tl - la * (u - l));
    lam_s[tid] = la;
    de_s[tid]  = dd;
    aux_s[tid] = (role == 8) ? (la * hd + mu) : 0.f;   // hh for role 8, rad acc else
    if (role == 8 && tid < N_IN) {
        float x = Xt[b * N_IN + tid], e = eps[b];
        float lo = fmaxf(x - e, CLAMP_MIN), up = fminf(x + e, CLAMP_MAX);
        hxr[tid] = 0.5f * (lo + up);
    }
    __syncthreads();

    if (role == 8) {
        float acc = bih[tid] + bhh[tid];
        #pragma unroll 8
        for (int i = 0; i < N_IN; ++i) acc += hxr[i] * Wih[i * H + tid];
        #pragma unroll 8
        for (int jj = 0; jj < H; ++jj) acc += aux_s[jj] * Whh[jj * H + tid];
        hp_new[b * H + tid] = acc;
        return;
    }

    u16* WTb  = WTp + (size_t)b * H * H;
    u16* errB = err + (size_t)b * ESTRIDE * H;
    const int diagRTbase = (E_old - H) >> 4;           // row-tile base of diag block

    // WT[n][k] = lam[k] * Whh[k][n], frag-packed, fully coalesced linear writes
    #pragma unroll 4
    for (int iter = 0; iter < 16; ++iter) {
        int p = (role * 16 + iter) * 256 + tid;
        int vb = (p & 1) * 2, h = (p >> 1) & 1, m = (p >> 2) & 15, qq = (p >> 6) & 3;
        int KC = (p >> 8) & 7, RT = p >> 11;
        int n = RT * 16 + m, k = KC * 32 + qq * 8 + h * 4 + vb;
        float w0 = WhhT32[(size_t)n * H + k], w1 = WhhT32[(size_t)n * H + k + 1];
        *(unsigned*)&WTb[2 * p] = (unsigned)f2bf(lam_s[k] * w0)
                                | ((unsigned)f2bf(lam_s[k + 1] * w1) << 16);
    }
    // diag rows: delta[i] * Whh[i][:]  (pre-multiplied by Whh, lam deferred)
    #pragma unroll 4
    for (int iter = 0; iter < 16; ++iter) {
        int p = (role * 16 + iter) * 256 + tid;
        int vb = (p & 1) * 2, h = (p >> 1) & 1, m = (p >> 2) & 15, qq = (p >> 6) & 3;
        int KC = (p >> 8) & 7, RT = p >> 11;
        int i = RT * 16 + m, k = KC * 32 + qq * 8 + h * 4 + vb;
        float dv = de_s[i];
        float v0 = dv * Whh[(size_t)i * H + k];
        float v1 = dv * Whh[(size_t)i * H + k + 1];
        *(unsigned*)&errB[(size_t)diagRTbase * 4096 + 2 * p] =
            (unsigned)f2bf(v0) | ((unsigned)f2bf(v1) << 16);
        atomicAdd(&aux_s[k],     fabsf(v0));
        atomicAdd(&aux_s[k + 1], fabsf(v1));
    }
    __syncthreads();
    atomicAdd(&rad_new[b * H + tid], aux_s[tid]);
}

// ---------------------------------------------------------------------------
// Main MFMA GEMM, in place: err[0..ntiles*64) <- err @ WT^T. grid (GNB, Bc).
// NEW: operand-swapped MFMA (C^T) -> direct coalesced global stores, no LDS
// transform. A staged via global_load_lds (double-buffered, 1 tile ahead);
// one raw s_barrier per tile with counted vmcnt(16) so C-stores stay in
// flight across the barrier. rad kept in registers, reduced once at end.
// ---------------------------------------------------------------------------
__global__ __launch_bounds__(256, 2) void gemm_k(
    u16* __restrict__ err, const u16* __restrict__ WTp,
    float* __restrict__ rad_new, int ntiles)
{
    __shared__ u16 sbuf[2][16384];          // 2 x 32 KB tile buffers
    const int b = blockIdx.y, tid = threadIdx.x;
    if (blockIdx.x >= ntiles) return;
    const int wave = tid >> 6, lane = tid & 63;
    const int m = lane & 15, q = lane >> 4;
    u16* errB = err + (size_t)b * ESTRIDE * H;
    const u16* WTb = WTp + (size_t)b * H * H;

    // B slab -> registers: wave owns n-cols [wave*64, wave*64+64), 128 VGPRs
    bf16x8 bf[4][8];
    #pragma unroll
    for (int nt = 0; nt < 4; ++nt)
        #pragma unroll
        for (int kc = 0; kc < 8; ++kc)
            bf[nt][kc] = *(const bf16x8*)
                &WTb[(size_t)(((((wave * 4 + nt) * 8 + kc) * 4 + q) << 7) + m * 8)];

    float racc[16];
    #pragma unroll
    for (int i = 0; i < 16; ++i) racc[i] = 0.f;

    // prologue: stage first tile
    int tile = blockIdx.x;
    {
        const u16* g = errB + (size_t)tile * 16384;
        #pragma unroll
        for (int r = 0; r < 8; ++r)
            gl_lds16(g + r * 2048 + tid * 8, &sbuf[0][r * 2048 + (tid >> 6) * 512]);
    }
    asm volatile("s_waitcnt vmcnt(0)" ::: "memory");
    __builtin_amdgcn_s_barrier();

    int cur = 0;
    for (; tile < ntiles; tile += GNB) {
        int nxt = tile + GNB;
        if (nxt < ntiles) {                  // prefetch next tile into other buffer
            const u16* g = errB + (size_t)nxt * 16384;
            #pragma unroll
            for (int r = 0; r < 8; ++r)
                gl_lds16(g + r * 2048 + tid * 8,
                         &sbuf[cur ^ 1][r * 2048 + (tid >> 6) * 512]);
        }

        f32x4 acc[4][4];
        #pragma unroll
        for (int i = 0; i < 4; ++i)
            #pragma unroll
            for (int c = 0; c < 4; ++c) acc[i][c] = (f32x4){0.f, 0.f, 0.f, 0.f};

        #pragma unroll
        for (int kc = 0; kc < 8; ++kc) {
            bf16x8 af[4];
            #pragma unroll
            for (int rt = 0; rt < 4; ++rt)
                af[rt] = *(const bf16x8*)
                    &sbuf[cur][(((rt * 8 + kc) * 4 + q) << 7) + m * 8];
            #pragma unroll
            for (int nt = 0; nt < 4; ++nt)
                #pragma unroll
                for (int rt = 0; rt < 4; ++rt)   // swapped: A=WT, B=err -> C^T
                    acc[rt][nt] = __builtin_amdgcn_mfma_f32_16x16x32_bf16(
                        bf[nt][kc], af[rt], acc[rt][nt], 0, 0, 0);
        }

        // C^T store: lane holds err-row r = rt*16+m, n = NT*16+q*4+v
        #pragma unroll
        for (int rt = 0; rt < 4; ++rt) {
            const size_t rowbase = (size_t)(tile * 4 + rt) * 4096;
            #pragma unroll
            for (int nt = 0; nt < 4; ++nt) {
                f32x4 v = acc[rt][nt];
                racc[nt * 4 + 0] += fabsf(v[0]);
                racc[nt * 4 + 1] += fabsf(v[1]);
                racc[nt * 4 + 2] += fabsf(v[2]);
                racc[nt * 4 + 3] += fabsf(v[3]);
                unsigned lo = (unsigned)f2bf(v[0]) | ((unsigned)f2bf(v[1]) << 16);
                unsigned hi = (unsigned)f2bf(v[2]) | ((unsigned)f2bf(v[3]) << 16);
                const int NT  = wave * 4 + nt;
                const int kcs = NT >> 1;
                const int qq  = (NT & 1) * 2 + (q >> 1);
                const size_t off16 = rowbase
                    + (size_t)((((kcs * 4 + qq) << 7) + m * 8 + (q & 1) * 4));
                *(u64*)&errB[off16] = ((u64)hi << 32) | lo;
            }
        }
        // counted wait: drains the 8 staging loads (older), leaves the 16
        // newest C-stores in flight across the barrier.
        asm volatile("s_waitcnt vmcnt(16)" ::: "memory");
        __builtin_amdgcn_s_barrier();
        cur ^= 1;
    }

    // rad: reduce over the 16 m-lanes, then one atomic per n from m==0 lanes
    #pragma unroll
    for (int i = 0; i < 16; ++i) {
        float v = racc[i];
        v += __shfl_xor(v, 1);
        v += __shfl_xor(v, 2);
        v += __shfl_xor(v, 4);
        v += __shfl_xor(v, 8);
        if (m == 0) {
            int nt = i >> 2, vv = i & 3;
            atomicAdd(&rad_new[b * H + wave * 64 + nt * 16 + q * 4 + vv], v);
        }
    }
}

// ---------------------------------------------------------------------------
__global__ __launch_bounds__(256) void tanh_final_k(
    const float* __restrict__ hp, const float* __restrict__ rad,
    float* __restrict__ lam, float* __restrict__ de, float* __restrict__ head_h)
{
    const int b = blockIdx.x, h = threadIdx.x;
    float hd = hp[b * H + h], r = rad[b * H + h];
    float l = hd - r, u = hd + r;
    float tl = tanhf(l), tu = tanhf(u);
    float la = fminf(1.f - tl * tl, 1.f - tu * tu);
    float mu = 0.5f * (tu + tl - la * (u + l));
    float dd = 0.5f * (tu - tl - la * (u - l));
    lam[b * H + h] = la;
    de[b * H + h]  = dd;
    head_h[b * H + h] = la * hd + mu;
}

// ---------------------------------------------------------------------------
// pack WoT frag-packed (layout B), lam folded. grid Bc x 256.
// ---------------------------------------------------------------------------
__global__ __launch_bounds__(256) void packWoT_k(
    const float* __restrict__ WoT32, const float* __restrict__ lam,
    u16* __restrict__ WoTp)
{
    const int b = blockIdx.x, tid = threadIdx.x;
    __shared__ float lam_s[H];
    lam_s[tid] = lam[b * H + tid];
    __syncthreads();
    u16* dst = WoTp + (size_t)b * N_OUT * H;
    #pragma unroll 4
    for (int iter = 0; iter < 32; ++iter) {
        int p = iter * 256 + tid;
        int vb = (p & 1) * 2, h = (p >> 1) & 1, m = (p >> 2) & 15, qq = (p >> 6) & 3;
        int KC = (p >> 8) & 7, RT = p >> 11;   // RT < 4
        int n = RT * 16 + m, k = KC * 32 + qq * 8 + h * 4 + vb;
        *(unsigned*)&dst[2 * p] =
              (unsigned)f2bf(lam_s[k]     * WoT32[(size_t)n * H + k])
            | ((unsigned)f2bf(lam_s[k + 1] * WoT32[(size_t)n * H + k + 1]) << 16);
    }
}

// ---------------------------------------------------------------------------
__global__ void head_out_k(
    const float* __restrict__ head_h, const float* __restrict__ de,
    const float* __restrict__ Wo, const float* __restrict__ bo,
    float* __restrict__ head_out, float* __restrict__ rad_out)
{
    const int b = blockIdx.x, o = threadIdx.x;
    float acc = bo[o], accR = 0.f;
    #pragma unroll 4
    for (int j = 0; j < H; ++j) {
        float w = Wo[j * N_OUT + o];
        acc  += head_h[b * H + j] * w;
        accR += fabsf(de[b * H + j] * w);
    }
    head_out[b * N_OUT + o] = acc;
    rad_out[b * N_OUT + o]  = accR;
}

// ---------------------------------------------------------------------------
// final radius: rad_out += sum_rows |err @ WoTp^T| over all ESTRIDE rows.
// Block 256 rows x 64 cols, 4 waves. grid (ESTRIDE/256, Bc). Layout-B loads.
// ---------------------------------------------------------------------------
__global__ __launch_bounds__(256) void gemm_out_k(
    const u16* __restrict__ err, const u16* __restrict__ WoTp,
    float* __restrict__ rad_out)
{
    __shared__ float rad_s[N_OUT];
    const int b = blockIdx.y, row0 = blockIdx.x * 256, tid = threadIdx.x;
    const int wave = tid >> 6, lane = tid & 63;
    const int m = lane & 15, q = lane >> 4;
    const u16* errB = err + (size_t)b * ESTRIDE * H;
    const u16* Wb   = WoTp + (size_t)b * N_OUT * H;

    if (tid < N_OUT) rad_s[tid] = 0.f;
    __syncthreads();

    f32x4 acc[4][4];
    #pragma unroll
    for (int i = 0; i < 4; ++i)
        #pragma unroll
        for (int c = 0; c < 4; ++c) acc[i][c] = (f32x4){0.f, 0.f, 0.f, 0.f};

    const int tile0 = (row0 >> 4) + wave * 4;
    #pragma unroll
    for (int kc = 0; kc < 8; ++kc) {
        bf16x8 af[4], bw[4];
        #pragma unroll
        for (int rt = 0; rt < 4; ++rt)
            af[rt] = *(const bf16x8*)
                &errB[(size_t)(((((tile0 + rt) * 8 + kc) * 4 + q) << 7) + m * 8)];
        #pragma unroll
        for (int nt = 0; nt < 4; ++nt)
            bw[nt] = *(const bf16x8*)
                &Wb[(size_t)((((nt * 8 + kc) * 4 + q) << 7) + m * 8)];
        #pragma unroll
        for (int nt = 0; nt < 4; ++nt)
            #pragma unroll
            for (int rt = 0; rt < 4; ++rt)
                acc[rt][nt] = __builtin_amdgcn_mfma_f32_16x16x32_bf16(
                    af[rt], bw[nt], acc[rt][nt], 0, 0, 0);
    }
    #pragma unroll
    for (int nt = 0; nt < 4; ++nt) {
        float s = 0.f;
        #pragma unroll
        for (int rt = 0; rt < 4; ++rt)
            #pragma unroll
            for (int r = 0; r < 4; ++r) s += fabsf(acc[rt][nt][r]);
        atomicAdd(&rad_s[nt * 16 + m], s);
    }
    __syncthreads();
    if (tid < N_OUT) atomicAdd(&rad_out[b * N_OUT + tid], rad_s[tid]);
}

// ---------------------------------------------------------------------------
__global__ void combine_k(const float* __restrict__ head_out,
                          const float* __restrict__ rad_out,
                          float* __restrict__ out)
{
    int i = blockIdx.x * 256 + threadIdx.x;
    if (i < BSZ * N_OUT) {
        float h = head_out[i], r = rad_out[i];
        out[i]               = h - r;
        out[BSZ * N_OUT + i] = h + r;
    }
}

// ---------------------------------------------------------------------------
extern "C" void kernel_launch(void* const* d_in, const int* in_sizes, int n_in,
                              void* d_out, int out_size, void* d_ws, size_t ws_size,
                              hipStream_t stream)
{
    const float* X    = (const float*)d_in[0];
    const float* eps  = (const float*)d_in[1];
    const float* Wih  = (const float*)d_in[2];
    const float* Whh  = (const float*)d_in[3];
    const float* bih  = (const float*)d_in[4];
    const float* bhh  = (const float*)d_in[5];
    const float* Wo   = (const float*)d_in[6];
    const float* bo   = (const float*)d_in[7];
    float* out = (float*)d_out;

    const size_t per_sample = (size_t)ESTRIDE * H * 2 + (size_t)H * H * 2
                            + (size_t)N_OUT * H * 2;
    const size_t shared_b = (size_t)H * H * 4 + (size_t)N_OUT * H * 4
                          + (size_t)2 * BSZ * H * 4                      // hp[2]
                          + (size_t)T_STEPS * BSZ * H * 4                // radT
                          + (size_t)3 * BSZ * H * 4                      // lam/de/head_h
                          + (size_t)2 * BSZ * N_OUT * 4 + 256;
    int Bc = BSZ;
    while (Bc > 1 && (size_t)Bc * per_sample + shared_b > ws_size) Bc >>= 1;

    char* p = (char*)d_ws;
    u16* errP      = (u16*)p;   p += (size_t)Bc * ESTRIDE * H * 2;
    u16* WTp       = (u16*)p;   p += (size_t)Bc * H * H * 2;
    u16* WoTp      = (u16*)p;   p += (size_t)Bc * N_OUT * H * 2;
    float* WhhT32  = (float*)p; p += (size_t)H * H * 4;
    float* WoT32   = (float*)p; p += (size_t)N_OUT * H * 4;
    float* hp      = (float*)p; p += (size_t)2 * BSZ * H * 4;
    float* radT    = (float*)p; p += (size_t)T_STEPS * BSZ * H * 4;
    float* lam     = (float*)p; p += (size_t)BSZ * H * 4;
    float* de      = (float*)p; p += (size_t)BSZ * H * 4;
    float* head_h  = (float*)p; p += (size_t)BSZ * H * 4;
    float* head_out= (float*)p; p += (size_t)BSZ * N_OUT * 4;
    float* rad_out = (float*)p;

    init_k<<<(T_STEPS * BSZ * H) / 256, 256, 0, stream>>>(radT);
    transpose_k<<<dim3(H / 32, H / 32), 256, 0, stream>>>(Whh, WhhT32, H, H);
    transpose_k<<<dim3(N_OUT / 32, H / 32), 256, 0, stream>>>(Wo, WoT32, H, N_OUT);

    for (int b0 = 0; b0 < BSZ; b0 += Bc) {
        prefresh_k<<<dim3(T_STEPS, Bc), 256, 0, stream>>>(
            X + (size_t)b0 * N_IN, eps + b0, Wih, errP, radT + (size_t)b0 * H);
        prep0_k<<<Bc, 256, 0, stream>>>(
            X + (size_t)b0 * N_IN, eps + b0, Wih, bih, bhh, hp + (size_t)b0 * H);
        for (int t = 1; t < T_STEPS; ++t) {
            int E_old = t * (N_IN + H);
            int ntiles = (E_old - H) / 64;   // 5t-4
            const float* hp_prev = hp + (size_t)((t - 1) & 1) * BSZ * H + (size_t)b0 * H;
            float*       hp_new  = hp + (size_t)(t & 1) * BSZ * H + (size_t)b0 * H;
            const float* rad_prev = radT + (size_t)(t - 1) * BSZ * H + (size_t)b0 * H;
            float*       rad_new  = radT + (size_t)t * BSZ * H + (size_t)b0 * H;
            mid_k<<<dim3(9, Bc), 256, 0, stream>>>(
                X + (size_t)(t * BSZ + b0) * N_IN, eps + b0, Wih, Whh, WhhT32,
                bih, bhh, hp_prev, rad_prev, hp_new, rad_new, errP, WTp, E_old);
            gemm_k<<<dim3(GNB, Bc), 256, 0, stream>>>(
                errP, WTp, rad_new, ntiles);
        }
        const float* hp_last = hp + (size_t)((T_STEPS - 1) & 1) * BSZ * H + (size_t)b0 * H;
        const float* rad_last = radT + (size_t)(T_STEPS - 1) * BSZ * H + (size_t)b0 * H;
        tanh_final_k<<<Bc, 256, 0, stream>>>(
            hp_last, rad_last, lam + (size_t)b0 * H, de + (size_t)b0 * H,
            head_h + (size_t)b0 * H);
        packWoT_k<<<Bc, 256, 0, stream>>>(WoT32, lam + (size_t)b0 * H, WoTp);
        head_out_k<<<Bc, 64, 0, stream>>>(
            head_h + (size_t)b0 * H, de + (size_t)b0 * H, Wo, bo,
            head_out + (size_t)b0 * N_OUT, rad_out + (size_t)b0 * N_OUT);
        gemm_out_k<<<dim3(ESTRIDE / 256, Bc), 256, 0, stream>>>(
            errP, WoTp, rad_out + (size_t)b0 * N_OUT);
    }

    combine_k<<<(BSZ * N_OUT + 255) / 256, 256, 0, stream>>>(head_out, rad_out, out);
}